// Round 14
// baseline (161.131 us; speedup 1.0000x reference)
//
#include <hip/hip_runtime.h>
#include <hip/hip_bf16.h>

#define N_NODES 10000
#define KNEI    30
#define DIM     128
#define EDGES   (N_NODES * KNEI)

typedef __attribute__((ext_vector_type(4))) float  f32x4;
typedef __attribute__((ext_vector_type(8))) __bf16 bf16x8;
typedef __attribute__((ext_vector_type(4))) __bf16 bf16x4;

// packed bf16 weight offsets in d_ws (element units); per-matrix fragment tiles
// AW1 (K=384, kt0..3 = hi part, kt4..11 = e|hj), others K=128/256, Ntiles=8.
// A3 = att_w3 [128][4] zero-padded to N=16 (1 n-tile, 4 k-tiles).
#define OFF_AW1 0        // 96 tiles
#define OFF_AW2 49152    // 32 tiles
#define OFF_NW1 65536    // 64 tiles
#define OFF_NW2 98304    // 32 tiles
#define OFF_NW3 114688   // 32 tiles
#define OFF_TH  131072   // 32 tiles
#define OFF_A3  147456   // 4 tiles
#define TOT_TILES 292
#define YHI_BYTE_OFF (300 * 1024)   // f32 yhi[N][128] after weights

// Pack all weights (f32) into MFMA A-fragment order, bf16, one launch.
// tile = kt*8+nt; lane holds n = nt*16+(lane&15), k = kt*32+(lane>>4)*8+i.
__global__ __launch_bounds__(256) void repack_all(
    const float* __restrict__ aw1, const float* __restrict__ aw2,
    const float* __restrict__ nw1, const float* __restrict__ nw2,
    const float* __restrict__ nw3, const float* __restrict__ thw,
    const float* __restrict__ aw3, __bf16* __restrict__ dst) {
    int t = blockIdx.x * 256 + threadIdx.x;
    if (t >= TOT_TILES * 512) return;
    int tile = t >> 9;
    int i    = t & 7;
    int lane = (t >> 3) & 63;
    int krow = ((lane >> 4) << 3) + i;
    int ncol = lane & 15;
    float v;
    if (tile >= 288) {                   // A3: aw3 [128][4] padded to 16 cols
        int k = (tile - 288) * 32 + krow;
        v = (ncol < 4) ? aw3[k * 4 + ncol] : 0.f;
    } else {
        const float* src; int lt;
        if      (tile < 96)  { src = aw1; lt = tile; }        // K=384
        else if (tile < 128) { src = aw2; lt = tile - 96; }
        else if (tile < 192) { src = nw1; lt = tile - 128; }  // K=256
        else if (tile < 224) { src = nw2; lt = tile - 192; }
        else if (tile < 256) { src = nw3; lt = tile - 224; }
        else                 { src = thw; lt = tile - 256; }
        int nt = lt & 7;
        int kt = lt >> 3;
        v = src[(kt * 32 + krow) * DIM + nt * 16 + ncol];
    }
    dst[t] = (__bf16)v;
}

// fast gelu: 0.5x(1+tanh(u)) = x - x/(exp(2u)+1)  (~8 VALU incl native rcp)
__device__ __forceinline__ float gelu_f(float x) {
    float y = x * fmaf(0.0713548163f, x * x, 1.5957691216f);  // 2u
    float r = __builtin_amdgcn_rcpf(__expf(y) + 1.f);
    return x - x * r;
}

__device__ __forceinline__ bf16x4 cvt4(float4 v) {
    bf16x4 r;
    r[0] = (__bf16)v.x; r[1] = (__bf16)v.y; r[2] = (__bf16)v.z; r[3] = (__bf16)v.w;
    return r;
}

#define ZERO2(A) do { A[0] = (f32x4){0.f,0.f,0.f,0.f}; A[1] = (f32x4){0.f,0.f,0.f,0.f}; } while (0)

// ---- generic 128->128 row GEMM (64 rows/block, 8 waves): out = in @ Wfrag (+bias) ----
__global__ __launch_bounds__(512) void mm128(const float* __restrict__ in,
                                             float* __restrict__ outp,
                                             const __bf16* __restrict__ wfrag,
                                             const float* __restrict__ bias) {
    __shared__ __bf16 sP[64 * 136];
    const int tid  = threadIdx.x;
    const int wv   = tid >> 6;
    const int lane = tid & 63;
    const int mrow = lane & 15;
    const int kgrp = lane >> 4;
    const int base = blockIdx.x * 64;

#pragma unroll
    for (int c = 0; c < 4; ++c) {
        int idx = c * 512 + tid;
        int m  = idx >> 5;
        int jv = idx & 31;
        int row = base + m;
        float4 v = make_float4(0.f, 0.f, 0.f, 0.f);
        if (row < N_NODES) v = *reinterpret_cast<const float4*>(in + (long)row * DIM + jv * 4);
        *reinterpret_cast<bf16x4*>(&sP[m * 136 + jv * 4]) = cvt4(v);
    }
    __syncthreads();

    f32x4 acc[4];
#pragma unroll
    for (int mf = 0; mf < 4; ++mf) acc[mf] = (f32x4){0.f, 0.f, 0.f, 0.f};
#pragma unroll
    for (int kt = 0; kt < 4; ++kt) {
        bf16x8 a = *reinterpret_cast<const bf16x8*>(wfrag + ((kt * 8 + wv) * 64 + lane) * 8);
        const int kb = kt * 32 + kgrp * 8;
#pragma unroll
        for (int mf = 0; mf < 4; ++mf) {
            bf16x8 b = *reinterpret_cast<const bf16x8*>(sP + (mf * 16 + mrow) * 136 + kb);
            acc[mf] = __builtin_amdgcn_mfma_f32_16x16x32_bf16(a, b, acc[mf], 0, 0, 0);
        }
    }
    const int nb = wv * 16 + kgrp * 4;
    float b0 = 0.f, b1 = 0.f, b2 = 0.f, b3 = 0.f;
    if (bias) { b0 = bias[nb]; b1 = bias[nb + 1]; b2 = bias[nb + 2]; b3 = bias[nb + 3]; }
#pragma unroll
    for (int mf = 0; mf < 4; ++mf) {
        int row = base + mf * 16 + mrow;
        if (row < N_NODES) {
            float4 o = make_float4(acc[mf][0] + b0, acc[mf][1] + b1,
                                   acc[mf][2] + b2, acc[mf][3] + b3);
            *reinterpret_cast<float4*>(outp + (long)row * DIM + nb) = o;
        }
    }
}

// ---- fused kernel: one block = 1 node (30 edges padded to 32), 256 thr = 4 waves ----
// Double-width n-slices: each ds_read_b128 feeds 2x the MFMAs of r13 (LDS pipe
// was ~50% busy and is the binding resource; r12 vs r13 showed occupancy >50%
// adds little). P1 merged (att+node share b-reads, wave owns 32n of each);
// P2 wave-split 64n/wave; P3 32n/wave + wave-0 MFMA logits; P4 fused agg.
// Per-node LDS b-reads ~264 -> ~136. VGPR ~56-72 expected -> 2-3 blocks/CU.
// launch_bounds min-waves kept LOW (cap 128): forcing a tighter cap spills
// ~75 MB scratch (r3/r6/r9 measured).
__global__ __launch_bounds__(256, 2) void gnn_fused(
    const float* __restrict__ h, const float* __restrict__ e, const int* __restrict__ eidx,
    const float* __restrict__ yhi,
    const float* __restrict__ ab2, const float* __restrict__ ab3,
    const float* __restrict__ nb1, const float* __restrict__ nb2, const float* __restrict__ nb3,
    const __bf16* __restrict__ wp, float* __restrict__ pre_out) {

    __shared__ __bf16 S[8704];        // staging e|hj (stride 264, 8448 used);
                                      // after P1: S' = node2-out @0, A2 = att2-out @4352 (stride 136)
    __shared__ __bf16 Y1[32 * 136];   // att1-out
    __shared__ __bf16 Y2[32 * 136];   // node1-out
    __shared__ float  sW[32][4];      // softmax weights (rows 30/31 = 0)

    const int tid  = threadIdx.x;
    const int wv   = tid >> 6;        // 0..3
    const int lane = tid & 63;
    const int mrow = lane & 15;
    const int kg   = (lane >> 4) & 3;
    const int node = blockIdx.x;
    const long ebase = (long)node * KNEI;

    // ---- P0: stage e|hj (f32 -> bf16), pad rows 30/31 = 0 ----
#pragma unroll
    for (int c = 0; c < 4; ++c) {
        int idx = c * 256 + tid;
        int m  = idx >> 5;   // row 0..31
        int jv = idx & 31;   // float4 col
        float4 ev = make_float4(0.f, 0.f, 0.f, 0.f), hjv = ev;
        if (m < KNEI) {
            long ge = ebase + m;
            ev  = *reinterpret_cast<const float4*>(e + ge * DIM + jv * 4);
            int dstn = eidx[EDGES + ge];
            hjv = *reinterpret_cast<const float4*>(h + (long)dstn * DIM + jv * 4);
        }
        *reinterpret_cast<bf16x4*>(&S[m * 264 + jv * 4])       = cvt4(ev);
        *reinterpret_cast<bf16x4*>(&S[m * 264 + 128 + jv * 4]) = cvt4(hjv);
    }
    __syncthreads();   // b0

    // ---- P1: MERGED layer-1 (K=256): wave owns 32 att-n AND 32 node-n ----
    {
        f32x4 aa[2][2], an[2][2];   // [n-frag j][m-frag]
#pragma unroll
        for (int j = 0; j < 2; ++j) { ZERO2(aa[j]); ZERO2(an[j]); }
        const __bf16* wA = wp + OFF_AW1 + 16384;   // att_w1 e|hj part (kt 4..11)
        const __bf16* wN = wp + OFF_NW1;
#pragma unroll
        for (int kt = 0; kt < 8; ++kt) {
            const int kb = kt * 32 + kg * 8;
            bf16x8 b0 = *reinterpret_cast<const bf16x8*>(S + mrow * 264 + kb);
            bf16x8 b1 = *reinterpret_cast<const bf16x8*>(S + (16 + mrow) * 264 + kb);
#pragma unroll
            for (int j = 0; j < 2; ++j) {
                bf16x8 a = *reinterpret_cast<const bf16x8*>(wA + ((kt * 8 + wv * 2 + j) * 64 + lane) * 8);
                aa[j][0] = __builtin_amdgcn_mfma_f32_16x16x32_bf16(a, b0, aa[j][0], 0, 0, 0);
                aa[j][1] = __builtin_amdgcn_mfma_f32_16x16x32_bf16(a, b1, aa[j][1], 0, 0, 0);
            }
#pragma unroll
            for (int j = 0; j < 2; ++j) {
                bf16x8 a = *reinterpret_cast<const bf16x8*>(wN + ((kt * 8 + wv * 2 + j) * 64 + lane) * 8);
                an[j][0] = __builtin_amdgcn_mfma_f32_16x16x32_bf16(a, b0, an[j][0], 0, 0, 0);
                an[j][1] = __builtin_amdgcn_mfma_f32_16x16x32_bf16(a, b1, an[j][1], 0, 0, 0);
            }
        }
        const float* yrow = yhi + (long)node * DIM;
#pragma unroll
        for (int j = 0; j < 2; ++j) {
            const int f = wv * 32 + j * 16 + kg * 4;
            float4 ba = *reinterpret_cast<const float4*>(yrow + f);
            float4 bn = *reinterpret_cast<const float4*>(nb1 + f);
            float bav[4] = {ba.x, ba.y, ba.z, ba.w};
            float bnv[4] = {bn.x, bn.y, bn.z, bn.w};
#pragma unroll
            for (int mf = 0; mf < 2; ++mf) {
                bf16x4 p1, p2;
#pragma unroll
                for (int r = 0; r < 4; ++r) {
                    p1[r] = (__bf16)fmaxf(aa[j][mf][r] + bav[r], 0.f);
                    p2[r] = (__bf16)gelu_f(an[j][mf][r] + bnv[r]);
                }
                *reinterpret_cast<bf16x4*>(Y1 + (mf * 16 + mrow) * 136 + f) = p1;
                *reinterpret_cast<bf16x4*>(Y2 + (mf * 16 + mrow) * 136 + f) = p2;
            }
        }
    }
    __syncthreads();   // b1 (S reads done; S free for S'/A2)

    // ---- P2: wave-split layer-2 (K=128): waves 0-1 att2 -> A2 (relu, 64n each);
    //      waves 2-3 node2 -> S' (gelu, 64n each) ----
    {
        const bool isatt = (wv < 2);
        const int w2 = isatt ? wv : (wv - 2);
        const __bf16* B = isatt ? Y1 : Y2;
        const __bf16* W = wp + (isatt ? OFF_AW2 : OFF_NW2);
        const float* bias = isatt ? ab2 : nb2;
        __bf16* dst = S + (isatt ? 4352 : 0);
        f32x4 acc[4][2];
#pragma unroll
        for (int j = 0; j < 4; ++j) ZERO2(acc[j]);
#pragma unroll
        for (int kt = 0; kt < 4; ++kt) {
            const int kb = kt * 32 + kg * 8;
            bf16x8 b0 = *reinterpret_cast<const bf16x8*>(B + mrow * 136 + kb);
            bf16x8 b1 = *reinterpret_cast<const bf16x8*>(B + (16 + mrow) * 136 + kb);
#pragma unroll
            for (int j = 0; j < 4; ++j) {
                bf16x8 a = *reinterpret_cast<const bf16x8*>(W + (size_t)((kt * 8 + w2 * 4 + j) * 64 + lane) * 8);
                acc[j][0] = __builtin_amdgcn_mfma_f32_16x16x32_bf16(a, b0, acc[j][0], 0, 0, 0);
                acc[j][1] = __builtin_amdgcn_mfma_f32_16x16x32_bf16(a, b1, acc[j][1], 0, 0, 0);
            }
        }
#pragma unroll
        for (int j = 0; j < 4; ++j) {
            const int f = w2 * 64 + j * 16 + kg * 4;
            float4 bb = *reinterpret_cast<const float4*>(bias + f);
            float bv[4] = {bb.x, bb.y, bb.z, bb.w};
#pragma unroll
            for (int mf = 0; mf < 2; ++mf) {
                bf16x4 pk;
#pragma unroll
                for (int r = 0; r < 4; ++r) {
                    float v = acc[j][mf][r] + bv[r];
                    pk[r] = (__bf16)(isatt ? fmaxf(v, 0.f) : gelu_f(v));
                }
                *reinterpret_cast<bf16x4*>(dst + (mf * 16 + mrow) * 136 + f) = pk;
            }
        }
    }
    __syncthreads();   // b2 (Y1/Y2 reads done; S' and A2 ready)

    // ---- P3: wave 0: logits via MFMA + softmax; all waves: node3 (32n, V in regs) ----
    if (wv == 0) {
        const __bf16* A2 = S + 4352;
        f32x4 la[2];
        ZERO2(la);
#pragma unroll
        for (int kt = 0; kt < 4; ++kt) {
            const int kb = kt * 32 + kg * 8;
            bf16x8 b0 = *reinterpret_cast<const bf16x8*>(A2 + mrow * 136 + kb);
            bf16x8 b1 = *reinterpret_cast<const bf16x8*>(A2 + (16 + mrow) * 136 + kb);
            bf16x8 a = *reinterpret_cast<const bf16x8*>(wp + OFF_A3 + ((kt * 64) + lane) * 8);
            la[0] = __builtin_amdgcn_mfma_f32_16x16x32_bf16(a, b0, la[0], 0, 0, 0);
            la[1] = __builtin_amdgcn_mfma_f32_16x16x32_bf16(a, b1, la[1], 0, 0, 0);
        }
        if (lane < 16) {   // lane = edge m; heads 0-3 in regs (kg==0 slice)
            const float sc = 0.17677669529f;   // 1/sqrt(32)
            float v0[4], v1[4], mx[4];
            const bool pad1 = (16 + lane) >= KNEI;
#pragma unroll
            for (int r = 0; r < 4; ++r) {
                v0[r] = (la[0][r] + ab3[r]) * sc;
                v1[r] = pad1 ? -1e30f : (la[1][r] + ab3[r]) * sc;
                mx[r] = fmaxf(v0[r], v1[r]);
            }
#pragma unroll
            for (int msk = 1; msk <= 8; msk <<= 1)
#pragma unroll
                for (int r = 0; r < 4; ++r) mx[r] = fmaxf(mx[r], __shfl_xor(mx[r], msk));
            float e0[4], e1[4], sm[4];
#pragma unroll
            for (int r = 0; r < 4; ++r) {
                e0[r] = __expf(v0[r] - mx[r]);
                e1[r] = __expf(v1[r] - mx[r]);   // pad -> 0
                sm[r] = e0[r] + e1[r];
            }
#pragma unroll
            for (int msk = 1; msk <= 8; msk <<= 1)
#pragma unroll
                for (int r = 0; r < 4; ++r) sm[r] += __shfl_xor(sm[r], msk);
            float i0 = __builtin_amdgcn_rcpf(sm[0]), i1 = __builtin_amdgcn_rcpf(sm[1]);
            float i2 = __builtin_amdgcn_rcpf(sm[2]), i3 = __builtin_amdgcn_rcpf(sm[3]);
            float4 w0 = make_float4(e0[0] * i0, e0[1] * i1, e0[2] * i2, e0[3] * i3);
            float4 w1 = make_float4(e1[0] * i0, e1[1] * i1, e1[2] * i2, e1[3] * i3);
            *reinterpret_cast<float4*>(&sW[lane][0])      = w0;
            *reinterpret_cast<float4*>(&sW[16 + lane][0]) = w1;   // rows 30/31 -> 0
        }
    }
    f32x4 v2[2][2];   // [n-frag j][m-frag]
#pragma unroll
    for (int j = 0; j < 2; ++j) ZERO2(v2[j]);
#pragma unroll
    for (int kt = 0; kt < 4; ++kt) {
        const int kb = kt * 32 + kg * 8;
        bf16x8 b0 = *reinterpret_cast<const bf16x8*>(S + mrow * 136 + kb);
        bf16x8 b1 = *reinterpret_cast<const bf16x8*>(S + (16 + mrow) * 136 + kb);
#pragma unroll
        for (int j = 0; j < 2; ++j) {
            bf16x8 a = *reinterpret_cast<const bf16x8*>(wp + OFF_NW3 + (size_t)((kt * 8 + wv * 2 + j) * 64 + lane) * 8);
            v2[j][0] = __builtin_amdgcn_mfma_f32_16x16x32_bf16(a, b0, v2[j][0], 0, 0, 0);
            v2[j][1] = __builtin_amdgcn_mfma_f32_16x16x32_bf16(a, b1, v2[j][1], 0, 0, 0);
        }
    }
    __syncthreads();   // b3 (sW visible; V in regs)

    // ---- P4: fused aggregation epilogue: pre[node][n] = sum_m w[m]*(V+nb3) ----
    // wave wv owns n [32wv, 32wv+32) = exactly head wv.
    {
        float wgt0 = sW[mrow][wv];        // edge m = mrow      (mf=0)
        float wgt1 = sW[16 + mrow][wv];   // edge m = 16 + mrow (mf=1)
        float part[2][4];
#pragma unroll
        for (int j = 0; j < 2; ++j)
#pragma unroll
            for (int r = 0; r < 4; ++r)
                part[j][r] = wgt0 * v2[j][0][r] + wgt1 * v2[j][1][r];
#pragma unroll
        for (int msk = 1; msk <= 8; msk <<= 1)
#pragma unroll
            for (int j = 0; j < 2; ++j)
#pragma unroll
                for (int r = 0; r < 4; ++r)
                    part[j][r] += __shfl_xor(part[j][r], msk);
        if (mrow == 0) {                  // lanes 0,16,32,48 -> kg 0..3
#pragma unroll
            for (int j = 0; j < 2; ++j) {
                const int nb = wv * 32 + j * 16 + kg * 4;
                float4 b3v = *reinterpret_cast<const float4*>(nb3 + nb);
                float4 o = make_float4(part[j][0] + b3v.x, part[j][1] + b3v.y,
                                       part[j][2] + b3v.z, part[j][3] + b3v.w);
                *reinterpret_cast<float4*>(pre_out + (long)node * DIM + nb) = o;
            }
        }
    }
}

extern "C" void kernel_launch(void* const* d_in, const int* in_sizes, int n_in,
                              void* d_out, int out_size, void* d_ws, size_t ws_size,
                              hipStream_t stream) {
    const float* h   = (const float*)d_in[0];
    const float* e   = (const float*)d_in[1];
    const int*   ei  = (const int*)d_in[2];
    const float* aw1 = (const float*)d_in[3];
    const float* ab1 = (const float*)d_in[4];
    const float* aw2 = (const float*)d_in[5];
    const float* ab2 = (const float*)d_in[6];
    const float* aw3 = (const float*)d_in[7];
    const float* ab3 = (const float*)d_in[8];
    const float* nw1 = (const float*)d_in[9];
    const float* nb1 = (const float*)d_in[10];
    const float* nw2 = (const float*)d_in[11];
    const float* nb2 = (const float*)d_in[12];
    const float* nw3 = (const float*)d_in[13];
    const float* nb3 = (const float*)d_in[14];
    const float* thw = (const float*)d_in[15];
    float* out = (float*)d_out;
    __bf16* wp = (__bf16*)d_ws;
    float* yhi = (float*)((char*)d_ws + YHI_BYTE_OFF);

    // all-weight repack (f32 -> bf16 MFMA-fragment order), one launch
    repack_all<<<(TOT_TILES * 512 + 255) / 256, 256, 0, stream>>>(
        aw1, aw2, nw1, nw2, nw3, thw, aw3, wp);

    const int nblk = (N_NODES + 63) / 64;
    // yhi = h @ att_w1[0:128,:] + ab1   (hi part of att layer 1, per node)
    mm128<<<nblk, 512, 0, stream>>>(h, yhi, wp + OFF_AW1, ab1);

    gnn_fused<<<N_NODES, 256, 0, stream>>>(h, e, ei, yhi, ab2, ab3,
                                           nb1, nb2, nb3, wp, out);
    // out = pre @ to_h_w (in-place)
    mm128<<<nblk, 512, 0, stream>>>(out, out, wp + OFF_TH, nullptr);
}